// Round 6
// baseline (146.908 us; speedup 1.0000x reference)
//
#include <hip/hip_runtime.h>

#define MT    132      // padded (M+1): 129 valid + 3 zero pad
#define NSEQ  512
#define LSEQ  256
#define MM    128      // M
#define NROW  129      // M+1
#define BETA  10.0     // reweighting: track a * e^{BETA*(t - mp)}
#define LOG2E 1.4426950408889634
#define LN2   0.6931471805599453

// per-mp transition tables (indexed by i = chain/source index), REWEIGHTED
enum { T_TMX=0, T_TIX, T_TMEQ0, T_TIEQ0, T_TMEQ1, T_TIEQ1,
       T_ENT0, T_ENT1, T_STP, T_I0, T_I1, T_COUNT };          // 11

#define TOK_BYTES (NSEQ*LSEQ)            // 131072 (uint8 tokens)
#define TABD_OFF  TOK_BYTES              // doubles, 8-aligned
#define TABD_CNT  (T_COUNT*MT)           // 1452 doubles
#define EMF_OFF   (TABD_OFF + TABD_CNT*8)
#define EMF_CNT   (2*25*MT)              // 6600 floats
#define EI_REL    (25*MT)                // 3300

// DPP ctrl encodings (gfx9/CDNA): ROW_SHR:d = 0x110+d, WAVE_SHR1 = 0x138,
// ROW_BCAST15 = 0x142, ROW_BCAST31 = 0x143.  (HW-verified in round 4.)
template <int CTRL, int RMASK, bool BC>
__device__ __forceinline__ double dpp_d(double v) {
  int lo = __double2loint(v), hi = __double2hiint(v);
  lo = __builtin_amdgcn_update_dpp(0, lo, CTRL, RMASK, 0xF, BC);
  hi = __builtin_amdgcn_update_dpp(0, hi, CTRL, RMASK, 0xF, BC);
  return __hiloint2double(hi, lo);
}

__device__ __forceinline__ double lse2d(double a, double b) {
  double m = fmax(a, b);
  return m + log(exp(a - m) + exp(b - m));
}

// ---------------------------------------------------------------- prep ----
__global__ void prep_kernel(const float* __restrict__ anc,
                            const float* __restrict__ insq,
                            const float* __restrict__ rr,
                            const float* __restrict__ uu,
                            double* __restrict__ tabd,
                            float* __restrict__ emf) {
  __shared__ double ls[T_COUNT*MT];
  const int tid = threadIdx.x;

  if (tid < MT) {
    double v[T_COUNT];
#pragma unroll
    for (int k = 0; k < T_COUNT; ++k) v[k] = 0.0;
    if (tid <= MM) {
      const int m = tid;
      double rn[3][2], un[3][2];
#pragma unroll
      for (int j = 0; j < 3; ++j) {
        double a0 = (double)rr[(m*3+j)*2+0], a1 = (double)rr[(m*3+j)*2+1];
        double l  = lse2d(a0, a1);
        rn[j][0] = a0 - l; rn[j][1] = a1 - l;
        double b0 = (double)uu[(m*3+j)*2+0], b1 = (double)uu[(m*3+j)*2+1];
        double l2 = lse2d(b0, b1);
        un[j][0] = b0 - l2; un[j][1] = b1 - l2;
      }
      v[T_TMX]   = exp(rn[0][0] + un[0][1] - BETA);  // match exit -> chain  (x e^-B)
      v[T_TIX]   = exp(rn[1][0] + un[1][1]);         // insert exit -> chain
      v[T_TMEQ0] = exp(rn[0][0] + un[0][0]);         // match -> (i,0)
      v[T_TIEQ0] = exp(rn[1][0] + un[1][0] + BETA);  // insert -> (i,0)      (x e^+B)
      v[T_TMEQ1] = exp(rn[0][1]);                    // match -> (i,1)
      v[T_TIEQ1] = exp(rn[1][1] + BETA);             // insert -> (i,1)      (x e^+B)
      v[T_ENT0]  = exp(rn[2][0] + un[2][0]);         // chain -> (mp,0)
      v[T_ENT1]  = exp(rn[2][1]);                    // chain -> (mp,1)
      v[T_STP]   = exp(rn[2][0] + un[2][1] - BETA);  // chain continue       (x e^-B)
    }
#pragma unroll
    for (int k = 0; k < T_COUNT; ++k) ls[k*MT + tid] = v[k];
  }
  __syncthreads();

  if (tid == 0) {   // initial dist (virtual source i=0,j=0), reweighted tables
    ls[T_I0*MT+0] = ls[T_TMEQ0*MT+0];
    ls[T_I1*MT+0] = ls[T_TMEQ1*MT+0];
    double c = ls[T_TMX*MT+0];
    for (int mp = 1; mp <= MM; ++mp) {
      ls[T_I0*MT+mp] = c * ls[T_ENT0*MT+mp];
      ls[T_I1*MT+mp] = c * ls[T_ENT1*MT+mp];
      c *= ls[T_STP*MT+mp];
    }
  }
  __syncthreads();

  for (int i = tid; i < T_COUNT*MT; i += blockDim.x) tabd[i] = ls[i];

  // emission tables: EM_T[d][m] = softmax(anc[m])[d] (transposed), d<24
  for (int row = tid; row < 2*NROW; row += blockDim.x) {
    const bool isM = row < NROW;
    const int  m   = isM ? row : row - NROW;
    const float* src = (isM ? anc : insq) + m*24;
    float* dst = emf + (isM ? 0 : EI_REL);
    float mx = -1e30f;
    for (int d = 0; d < 24; ++d) mx = fmaxf(mx, src[d]);
    float s = 0.f;
    for (int d = 0; d < 24; ++d) s += __expf(src[d] - mx);
    float is = 1.f / s;
    for (int d = 0; d < 24; ++d) dst[d*MT + m] = __expf(src[d] - mx) * is;
  }
  // masked-token row (tok==24) = 1.0 on valid cols, 0 on pads
  for (int i = tid; i < MT; i += blockDim.x) {
    float v = (i <= MM) ? 1.f : 0.f;
    emf[         24*MT + i] = v;
    emf[EI_REL + 24*MT + i] = v;
  }
  // zero pad cols (129..131) of token rows d<24, both tables
  for (int i = tid; i < 2*24*3; i += blockDim.x) {
    int which = i / 72, rem = i % 72, d = rem / 3, c = NROW + rem % 3;
    emf[which*EI_REL + d*MT + c] = 0.f;
  }
}

// ---------------------------------------------------------------- tok -----
__global__ void tok_kernel(const float* __restrict__ data,
                           unsigned char* __restrict__ toks) {
  const int t = threadIdx.x;
  const int n = blockIdx.x;
  const float* p = data + (size_t)(n*LSEQ + t)*24;
  int tok = 24;
#pragma unroll
  for (int d = 0; d < 24; ++d) if (p[d] > 0.5f) tok = d;
  toks[n*LSEQ + t] = (unsigned char)tok;
}

// ---------------------------------------------------------------- fwd -----
// fp64 recurrence (round-4 numerics: required window is ~beta*M nats because
// the final unweighting adds +beta*mp; only fp64 holds it). TWO sequences
// per wave, ILP-interleaved: seq B's instruction stream fills seq A's
// dependency-chain stalls (1 wave/SIMD -> nothing else fills them).
__global__ __launch_bounds__(64)
void fwd_kernel(const double* __restrict__ tabd,
                const float* __restrict__ emf,
                const unsigned char* __restrict__ toks,
                float* __restrict__ out) {
  __shared__ double ldsE[EMF_CNT];     // emissions as double: no per-step cvt
  __shared__ int    ldsT[2][LSEQ];
  const int lane = threadIdx.x;
  const int n0   = blockIdx.x * 2;

  for (int i = lane; i < EMF_CNT; i += 64) ldsE[i] = (double)emf[i];
#pragma unroll
  for (int s = 0; s < 2; ++s) {
    const unsigned char* tp = toks + (size_t)(n0 + s)*LSEQ;
    for (int i = lane; i < LSEQ; i += 64) ldsT[s][i] = (int)tp[i] * MT;
  }

  const int mp0 = 3*lane;
  double tmx[3], tix[3], te0m[3], te0i[3], te1m[3], te1i[3],
         en0[3], en1[3], stpd[3], i0v[3], i1v[3];
  int col[3];
#pragma unroll
  for (int j = 0; j < 3; ++j) {
    int mp = mp0 + j;
    bool ok = mp < MT;
    col[j] = ok ? mp : (MT-1);
    int ix = ok ? mp : 0;
    tmx[j]  = ok ? tabd[T_TMX  *MT+ix] : 0.0;
    tix[j]  = ok ? tabd[T_TIX  *MT+ix] : 0.0;
    te0m[j] = ok ? tabd[T_TMEQ0*MT+ix] : 0.0;
    te0i[j] = ok ? tabd[T_TIEQ0*MT+ix] : 0.0;
    te1m[j] = ok ? tabd[T_TMEQ1*MT+ix] : 0.0;
    te1i[j] = ok ? tabd[T_TIEQ1*MT+ix] : 0.0;
    en0[j]  = ok ? tabd[T_ENT0 *MT+ix] : 0.0;
    en1[j]  = ok ? tabd[T_ENT1 *MT+ix] : 0.0;
    stpd[j] = ok ? tabd[T_STP  *MT+ix] : 0.0;
    i0v[j]  = ok ? tabd[T_I0   *MT+ix] : 0.0;
    i1v[j]  = ok ? tabd[T_I1   *MT+ix] : 0.0;
  }
  const double stp0  = stpd[0], stp1 = stpd[1];
  const double s2v   = stpd[2];
  const double s12   = stpd[1]*stpd[2];
  const double stp01 = stpd[0]*stpd[1];

  // loop-invariant DPP-scan window multipliers (log-space preamble)
  double W1, W2, W4, W8, W5, W6;
  {
    double p = stpd[0]*stpd[1]*stpd[2];
    double lp = (p > 0.0) ? log(p) : -745.0;
    double LP = lp;
#pragma unroll
    for (int r = 0; r < 6; ++r) {
      double tq = __shfl_up(LP, 1 << r);
      if (lane >= (1 << r)) LP += tq;
    }
    double LPm1 = __shfl_up(LP, 1), LPm2 = __shfl_up(LP, 2),
           LPm4 = __shfl_up(LP, 4), LPm8 = __shfl_up(LP, 8);
    double LP31 = __shfl(LP, 31);
    int rs = lane & ~15;
    double LPrsm1 = __shfl(LP, rs > 0 ? rs - 1 : 0);
    int rl = lane & 15;
    W1 = (rl >= 1)   ? exp(LP - LPm1)   : 0.0;
    W2 = (rl >= 2)   ? exp(LP - LPm2)   : 0.0;
    W4 = (rl >= 4)   ? exp(LP - LPm4)   : 0.0;
    W8 = (rl >= 8)   ? exp(LP - LPm8)   : 0.0;
    W5 = (lane & 16) ? exp(LP - LPrsm1) : 0.0;   // rows 1,3
    W6 = (lane >= 32)? exp(LP - LP31)   : 0.0;   // rows 2,3
  }
  __syncthreads();

  // initial alpha + first emission prefetch, per sequence
  double aM[2][3], aI[2][3], fcm[2][3], fci[2][3];
  int acc2i[2] = {0, 0};
#pragma unroll
  for (int s = 0; s < 2; ++s) {
    int t0 = ldsT[s][0];
#pragma unroll
    for (int j = 0; j < 3; ++j) {
      aM[s][j] = i0v[j] * ldsE[t0 + col[j]];
      aI[s][j] = i1v[j] * ldsE[EI_REL + t0 + col[j]];
    }
    int tf = ldsT[s][1];
#pragma unroll
    for (int j = 0; j < 3; ++j) {
      fcm[s][j] = ldsE[tf + col[j]];
      fci[s][j] = ldsE[EI_REL + tf + col[j]];
    }
  }

  for (int t = 1; t < LSEQ; ++t) {
    const int tn = (t + 1 < LSEQ) ? t + 1 : t;
#pragma unroll
    for (int s = 0; s < 2; ++s) {
      // prefetch next step's emissions (off critical path)
      int tfN = ldsT[s][tn];
      double fnm[3], fni[3];
#pragma unroll
      for (int j = 0; j < 3; ++j) {
        fnm[j] = ldsE[tfN + col[j]];
        fni[j] = ldsE[EI_REL + tfN + col[j]];
      }

      double ap0 = dpp_d<0x138, 0xF, true>(aM[s][2]);  // wave_shr:1, lane0->0
      double ap[3] = {ap0, aM[s][0], aM[s][1]};
      double X[3], e0m[3], e1m[3], g0[3], g1[3];
#pragma unroll
      for (int j = 0; j < 3; ++j) {
        X[j]   = fma(ap[j], tmx[j],  aI[s][j]*tix[j]);     // feeds delete chain
        double e0 = fma(ap[j], te0m[j], aI[s][j]*te0i[j]); // direct -> (mp,0)
        double e1 = fma(ap[j], te1m[j], aI[s][j]*te1i[j]); // direct -> (mp,1)
        e0m[j] = e0 * fcm[s][j];           // pre-multiplied by emission
        e1m[j] = e1 * fci[s][j];
        g0[j]  = en0[j] * fcm[s][j];       // chain-entry x emission (off chain)
        g1[j]  = en1[j] * fci[s][j];
      }
      // local composite, then 6-round DPP affine scan (64-lane inclusive)
      double x = fma(X[0], s12, fma(X[1], s2v, X[2]));
      double pre = fma(X[0], stp1, X[1]);            // off-chain for C2
      double xs;
      xs = dpp_d<0x111, 0xF, true >(x); x = fma(xs, W1, x);  // row_shr:1
      xs = dpp_d<0x112, 0xF, true >(x); x = fma(xs, W2, x);  // row_shr:2
      xs = dpp_d<0x114, 0xF, true >(x); x = fma(xs, W4, x);  // row_shr:4
      xs = dpp_d<0x118, 0xF, true >(x); x = fma(xs, W8, x);  // row_shr:8
      xs = dpp_d<0x142, 0xA, false>(x); x = fma(xs, W5, x);  // bcast15 -> rows 1,3
      xs = dpp_d<0x143, 0xC, false>(x); x = fma(xs, W6, x);  // bcast31 -> rows 2,3
      double C0 = dpp_d<0x138, 0xF, true>(x);                // wave_shr:1
      double C1 = fma(C0, stp0,  X[0]);
      double C2 = fma(C0, stp01, pre);    // == fma(C1, stp1, X[1]) reassociated
      double Cv[3] = {C0, C1, C2};
#pragma unroll
      for (int j = 0; j < 3; ++j) {
        aM[s][j] = fma(Cv[j], g0[j], e0m[j]);
        aI[s][j] = fma(Cv[j], g1[j], e1m[j]);
        fcm[s][j] = fnm[j]; fci[s][j] = fni[j];
      }
    }
    // exact exponent-only renorm every 8 steps (target max ~= 2^500)
    if ((t & 7) == 0) {
#pragma unroll
      for (int s = 0; s < 2; ++s) {
        double m = fmax(fmax(fmax(aM[s][0],aM[s][1]), fmax(aM[s][2],aI[s][0])),
                        fmax(aI[s][1],aI[s][2]));
        m = fmax(m, dpp_d<0x111, 0xF, true >(m));
        m = fmax(m, dpp_d<0x112, 0xF, true >(m));
        m = fmax(m, dpp_d<0x114, 0xF, true >(m));
        m = fmax(m, dpp_d<0x118, 0xF, true >(m));
        m = fmax(m, dpp_d<0x142, 0xA, false>(m));
        m = fmax(m, dpp_d<0x143, 0xC, false>(m));
        int ehi = __builtin_amdgcn_readlane(__double2hiint(m), 63);
        int er  = (ehi >> 20) & 0x7FF;
        int dl  = er ? (1523 - er) : 0;     // multiply by 2^dl -> max ~ 2^500
        acc2i[s] -= dl;
        double sc = __hiloint2double((1023 + dl) << 20, 0);
#pragma unroll
        for (int j = 0; j < 3; ++j) { aM[s][j] *= sc; aI[s][j] *= sc; }
      }
    }
  }

  // final: undo reweighting per state (log2 a = log2 a~ + B*log2e*mp + acc2)
#pragma unroll
  for (int s = 0; s < 2; ++s) {
    double l2[6];
#pragma unroll
    for (int j = 0; j < 3; ++j) {
      double vm = aM[s][j], vi = aI[s][j];
      double w = BETA * LOG2E * (double)(mp0 + j);
      l2[j]   = (vm > 0.0 ? log2(vm) + w : -1.0e300);
      l2[3+j] = (vi > 0.0 ? log2(vi) + w : -1.0e300);
    }
    double lm = l2[0];
#pragma unroll
    for (int j = 1; j < 6; ++j) lm = fmax(lm, l2[j]);
#pragma unroll
    for (int r = 0; r < 6; ++r) lm = fmax(lm, __shfl_xor(lm, 1 << r));
    lm = fmax(lm, -1.0e280);
    double sum = 0.0;
#pragma unroll
    for (int j = 0; j < 6; ++j) sum += exp2(l2[j] - lm);
#pragma unroll
    for (int r = 0; r < 6; ++r) sum += __shfl_xor(sum, 1 << r);
    if (lane == 0) {
      // correction: -255*BETA nats (e^{B t} reweight at t=255)
      out[n0+s] = (float)(LN2*(lm + (double)acc2i[s] + log2(sum)) - 255.0*BETA);
    }
  }
}

// ---------------------------------------------------------------- launch --
extern "C" void kernel_launch(void* const* d_in, const int* in_sizes, int n_in,
                              void* d_out, int out_size, void* d_ws, size_t ws_size,
                              hipStream_t stream) {
  const float* anc  = (const float*)d_in[0];
  const float* insq = (const float*)d_in[1];
  const float* rr   = (const float*)d_in[2];
  const float* uu   = (const float*)d_in[3];
  const float* data = (const float*)d_in[4];
  float* out = (float*)d_out;

  unsigned char* toks = (unsigned char*)d_ws;
  double* tabd = (double*)((char*)d_ws + TABD_OFF);
  float*  emf  = (float*) ((char*)d_ws + EMF_OFF);

  hipLaunchKernelGGL(prep_kernel, dim3(1),      dim3(256), 0, stream,
                     anc, insq, rr, uu, tabd, emf);
  hipLaunchKernelGGL(tok_kernel,  dim3(NSEQ),   dim3(LSEQ), 0, stream, data, toks);
  hipLaunchKernelGGL(fwd_kernel,  dim3(NSEQ/2), dim3(64),  0, stream,
                     tabd, emf, toks, out);
}

// Round 7
// 84.934 us; speedup vs baseline: 1.7297x; 1.7297x over previous
//
#include <hip/hip_runtime.h>

#define MT    132      // padded (M+1): 129 valid + 3 zero pad
#define NSEQ  512
#define LSEQ  256
#define MM    128      // M
#define NROW  129      // M+1
#define BETA  10.0     // reweighting: track a * e^{BETA*(t - mp)}
#define LOG2E 1.4426950408889634
#define LN2   0.6931471805599453

// per-mp transition tables (indexed by i = chain/source index), REWEIGHTED
enum { T_TMX=0, T_TIX, T_TMEQ0, T_TIEQ0, T_TMEQ1, T_TIEQ1,
       T_ENT0, T_ENT1, T_STP, T_I0, T_I1, T_COUNT };          // 11

// ws layout: [int tokoff NSEQ*LSEQ] [tabd doubles] [emd doubles, 16B-aligned]
#define TOKI_BYTES (NSEQ*LSEQ*4)          // 524288
#define TABD_OFF   TOKI_BYTES
#define TABD_CNT   (T_COUNT*MT)           // 1452 doubles
#define EMD_OFF    (TABD_OFF + TABD_CNT*8) // 535904 (16-aligned)
#define EMD_ROW_B  (MT*16)                // 2112 bytes per token row (col pairs)

// DPP ctrl encodings (gfx9/CDNA): ROW_SHR:d = 0x110+d, WAVE_SHR1 = 0x138,
// ROW_BCAST15 = 0x142, ROW_BCAST31 = 0x143.  (HW-verified in round 4.)
template <int CTRL, int RMASK, bool BC>
__device__ __forceinline__ double dpp_d(double v) {
  int lo = __double2loint(v), hi = __double2hiint(v);
  lo = __builtin_amdgcn_update_dpp(0, lo, CTRL, RMASK, 0xF, BC);
  hi = __builtin_amdgcn_update_dpp(0, hi, CTRL, RMASK, 0xF, BC);
  return __hiloint2double(hi, lo);
}

__device__ __forceinline__ double lse2d(double a, double b) {
  double m = fmax(a, b);
  return m + log(exp(a - m) + exp(b - m));
}

// ---------------------------------------------------------- prep + tok ----
// block 0: transition tables + interleaved emission table
// blocks 1..NSEQ: token decode for sequence (blockIdx-1)
__global__ void prep_tok_kernel(const float* __restrict__ anc,
                                const float* __restrict__ insq,
                                const float* __restrict__ rr,
                                const float* __restrict__ uu,
                                const float* __restrict__ data,
                                double* __restrict__ tabd,
                                double* __restrict__ emd,
                                int* __restrict__ tokoff) {
  const int tid = threadIdx.x;
  if (blockIdx.x != 0) {
    // ---- token decode: one thread per position, float4 loads ----
    const int n = blockIdx.x - 1;
    const float4* p = (const float4*)(data + (size_t)(n*LSEQ + tid)*24);
    int tok = 24;
#pragma unroll
    for (int q = 0; q < 6; ++q) {
      float4 v = p[q];
      if (v.x > 0.5f) tok = 4*q+0;
      if (v.y > 0.5f) tok = 4*q+1;
      if (v.z > 0.5f) tok = 4*q+2;
      if (v.w > 0.5f) tok = 4*q+3;
    }
    tokoff[n*LSEQ + tid] = tok * EMD_ROW_B;   // byte offset of token row
    return;
  }

  // ---- block 0: tables ----
  __shared__ double ls[T_COUNT*MT];
  if (tid < MT) {
    double v[T_COUNT];
#pragma unroll
    for (int k = 0; k < T_COUNT; ++k) v[k] = 0.0;
    if (tid <= MM) {
      const int m = tid;
      double rn[3][2], un[3][2];
#pragma unroll
      for (int j = 0; j < 3; ++j) {
        double a0 = (double)rr[(m*3+j)*2+0], a1 = (double)rr[(m*3+j)*2+1];
        double l  = lse2d(a0, a1);
        rn[j][0] = a0 - l; rn[j][1] = a1 - l;
        double b0 = (double)uu[(m*3+j)*2+0], b1 = (double)uu[(m*3+j)*2+1];
        double l2 = lse2d(b0, b1);
        un[j][0] = b0 - l2; un[j][1] = b1 - l2;
      }
      v[T_TMX]   = exp(rn[0][0] + un[0][1] - BETA);  // match exit -> chain  (x e^-B)
      v[T_TIX]   = exp(rn[1][0] + un[1][1]);         // insert exit -> chain
      v[T_TMEQ0] = exp(rn[0][0] + un[0][0]);         // match -> (i,0)
      v[T_TIEQ0] = exp(rn[1][0] + un[1][0] + BETA);  // insert -> (i,0)      (x e^+B)
      v[T_TMEQ1] = exp(rn[0][1]);                    // match -> (i,1)
      v[T_TIEQ1] = exp(rn[1][1] + BETA);             // insert -> (i,1)      (x e^+B)
      v[T_ENT0]  = exp(rn[2][0] + un[2][0]);         // chain -> (mp,0)
      v[T_ENT1]  = exp(rn[2][1]);                    // chain -> (mp,1)
      v[T_STP]   = exp(rn[2][0] + un[2][1] - BETA);  // chain continue       (x e^-B)
    }
#pragma unroll
    for (int k = 0; k < T_COUNT; ++k) ls[k*MT + tid] = v[k];
  }
  __syncthreads();

  if (tid == 0) {   // initial dist (virtual source i=0,j=0), reweighted tables
    ls[T_I0*MT+0] = ls[T_TMEQ0*MT+0];
    ls[T_I1*MT+0] = ls[T_TMEQ1*MT+0];
    double c = ls[T_TMX*MT+0];
    for (int mp = 1; mp <= MM; ++mp) {
      ls[T_I0*MT+mp] = c * ls[T_ENT0*MT+mp];
      ls[T_I1*MT+mp] = c * ls[T_ENT1*MT+mp];
      c *= ls[T_STP*MT+mp];
    }
  }
  __syncthreads();

  for (int i = tid; i < T_COUNT*MT; i += blockDim.x) tabd[i] = ls[i];

  // ---- interleaved emission table: emd[(d*MT+col)*2 + {0:match,1:ins}] ----
  if (tid < NROW) {
    const int m = tid;
    const float* sa = anc  + m*24;
    const float* si = insq + m*24;
    float mxa = -1e30f, mxi = -1e30f;
    for (int d = 0; d < 24; ++d) { mxa = fmaxf(mxa, sa[d]); mxi = fmaxf(mxi, si[d]); }
    float ssa = 0.f, ssi = 0.f;
    for (int d = 0; d < 24; ++d) { ssa += __expf(sa[d]-mxa); ssi += __expf(si[d]-mxi); }
    float ia = 1.f/ssa, ii = 1.f/ssi;
    for (int d = 0; d < 24; ++d) {
      emd[(d*MT+m)*2+0] = (double)(__expf(sa[d]-mxa)*ia);
      emd[(d*MT+m)*2+1] = (double)(__expf(si[d]-mxi)*ii);
    }
    emd[(24*MT+m)*2+0] = 1.0;   // masked token row
    emd[(24*MT+m)*2+1] = 1.0;
  }
  // pad cols 129..131, all 25 token rows
  for (int i = tid; i < 25*3; i += blockDim.x) {
    int d = i/3, c = NROW + i%3;
    emd[(d*MT+c)*2+0] = 0.0;
    emd[(d*MT+c)*2+1] = 0.0;
  }
}

// ---------------------------------------------------------------- fwd -----
// fp64 recurrence (round-4 numerics — the final unweighting adds +beta*mp so
// the survival window is ~beta*M nats; only fp64 holds it). One sequence per
// wave, 512 blocks. Emissions read from GLOBAL (L2-resident 52.8 KB table)
// as 3x dwordx4 per step with 2-step-ahead prefetch.
struct E6 { double2 a, b, c; };

__global__ __launch_bounds__(64)
void fwd_kernel(const double* __restrict__ tabd,
                const double* __restrict__ emd,
                const int* __restrict__ tokoff,
                float* __restrict__ out) {
  __shared__ int ldsT[LSEQ];
  const int lane = threadIdx.x;
  const int n    = blockIdx.x;

  const int* tp = tokoff + n*LSEQ;
  for (int i = lane; i < LSEQ; i += 64) ldsT[i] = tp[i];

  const int mp0 = 3*lane;
  double tmx[3], tix[3], te0m[3], te0i[3], te1m[3], te1i[3],
         en0[3], en1[3], stpd[3], i0v[3], i1v[3];
#pragma unroll
  for (int j = 0; j < 3; ++j) {
    int mp = mp0 + j;
    bool ok = mp < MT;
    int ix = ok ? mp : 0;
    tmx[j]  = ok ? tabd[T_TMX  *MT+ix] : 0.0;
    tix[j]  = ok ? tabd[T_TIX  *MT+ix] : 0.0;
    te0m[j] = ok ? tabd[T_TMEQ0*MT+ix] : 0.0;
    te0i[j] = ok ? tabd[T_TIEQ0*MT+ix] : 0.0;
    te1m[j] = ok ? tabd[T_TMEQ1*MT+ix] : 0.0;
    te1i[j] = ok ? tabd[T_TIEQ1*MT+ix] : 0.0;
    en0[j]  = ok ? tabd[T_ENT0 *MT+ix] : 0.0;
    en1[j]  = ok ? tabd[T_ENT1 *MT+ix] : 0.0;
    stpd[j] = ok ? tabd[T_STP  *MT+ix] : 0.0;
    i0v[j]  = ok ? tabd[T_I0   *MT+ix] : 0.0;
    i1v[j]  = ok ? tabd[T_I1   *MT+ix] : 0.0;
  }
  const double stp0  = stpd[0], stp1 = stpd[1];
  const double s2v   = stpd[2];
  const double s12   = stpd[1]*stpd[2];
  const double stp01 = stpd[0]*stpd[1];

  // loop-invariant DPP-scan window multipliers (log-space preamble)
  double W1, W2, W4, W8, W5, W6;
  {
    double p = stpd[0]*stpd[1]*stpd[2];
    double lp = (p > 0.0) ? log(p) : -745.0;
    double LP = lp;
#pragma unroll
    for (int r = 0; r < 6; ++r) {
      double tq = __shfl_up(LP, 1 << r);
      if (lane >= (1 << r)) LP += tq;
    }
    double LPm1 = __shfl_up(LP, 1), LPm2 = __shfl_up(LP, 2),
           LPm4 = __shfl_up(LP, 4), LPm8 = __shfl_up(LP, 8);
    double LP31 = __shfl(LP, 31);
    int rs = lane & ~15;
    double LPrsm1 = __shfl(LP, rs > 0 ? rs - 1 : 0);
    int rl = lane & 15;
    W1 = (rl >= 1)   ? exp(LP - LPm1)   : 0.0;
    W2 = (rl >= 2)   ? exp(LP - LPm2)   : 0.0;
    W4 = (rl >= 4)   ? exp(LP - LPm4)   : 0.0;
    W8 = (rl >= 8)   ? exp(LP - LPm8)   : 0.0;
    W5 = (lane & 16) ? exp(LP - LPrsm1) : 0.0;   // rows 1,3
    W6 = (lane >= 32)? exp(LP - LP31)   : 0.0;   // rows 2,3
  }
  __syncthreads();

  // per-lane emission base (clamped so pad lanes stay in-bounds; their
  // tables are all-zero so the values read are never used)
  const int lx = (lane < 44) ? lane : 43;
  const char* emB = (const char*)emd + (size_t)lx*48;
  auto loadE = [&](int t) {
    int off = ldsT[t];
    E6 e;
    e.a = *(const double2*)(emB + off);
    e.b = *(const double2*)(emB + off + 16);
    e.c = *(const double2*)(emB + off + 32);
    return e;
  };

  // initial alpha (reweighted linear domain, fp64)
  double aM[3], aI[3];
  {
    E6 e0 = loadE(0);
    aM[0] = i0v[0]*e0.a.x;  aI[0] = i1v[0]*e0.a.y;
    aM[1] = i0v[1]*e0.b.x;  aI[1] = i1v[1]*e0.b.y;
    aM[2] = i0v[2]*e0.c.x;  aI[2] = i1v[2]*e0.c.y;
  }
  int acc2i = 0;

  E6 cur = loadE(1);
  E6 nxt = loadE(2);

  for (int t = 1; t < LSEQ; ++t) {
    E6 nn = loadE(t + 2 <= LSEQ-1 ? t + 2 : LSEQ-1);   // 2-deep prefetch

    const double em[3] = {cur.a.x, cur.b.x, cur.c.x};
    const double ei[3] = {cur.a.y, cur.b.y, cur.c.y};

    double ap0 = dpp_d<0x138, 0xF, true>(aM[2]);   // wave_shr:1, lane0 -> 0
    double ap[3] = {ap0, aM[0], aM[1]};
    double X[3], e0m[3], e1m[3], g0[3], g1[3];
#pragma unroll
    for (int j = 0; j < 3; ++j) {
      X[j] = fma(ap[j], tmx[j],  aI[j]*tix[j]);       // feeds delete chain
      double e0 = fma(ap[j], te0m[j], aI[j]*te0i[j]); // direct -> (mp,0)
      double e1 = fma(ap[j], te1m[j], aI[j]*te1i[j]); // direct -> (mp,1)
      e0m[j] = e0 * em[j];          // pre-multiplied by emission (off chain)
      e1m[j] = e1 * ei[j];
      g0[j]  = en0[j] * em[j];
      g1[j]  = en1[j] * ei[j];
    }
    // local composite, then 6-round DPP affine scan (64-lane inclusive)
    double x = fma(X[0], s12, fma(X[1], s2v, X[2]));
    double pre = fma(X[0], stp1, X[1]);               // off-chain for C2
    double xs;
    xs = dpp_d<0x111, 0xF, true >(x); x = fma(xs, W1, x);  // row_shr:1
    xs = dpp_d<0x112, 0xF, true >(x); x = fma(xs, W2, x);  // row_shr:2
    xs = dpp_d<0x114, 0xF, true >(x); x = fma(xs, W4, x);  // row_shr:4
    xs = dpp_d<0x118, 0xF, true >(x); x = fma(xs, W8, x);  // row_shr:8
    xs = dpp_d<0x142, 0xA, false>(x); x = fma(xs, W5, x);  // bcast15 -> rows 1,3
    xs = dpp_d<0x143, 0xC, false>(x); x = fma(xs, W6, x);  // bcast31 -> rows 2,3
    double C0 = dpp_d<0x138, 0xF, true>(x);                // wave_shr:1
    double C1 = fma(C0, stp0,  X[0]);
    double C2 = fma(C0, stp01, pre);    // == fma(C1, stp1, X[1]) reassociated
    aM[0] = fma(C0, g0[0], e0m[0]);  aI[0] = fma(C0, g1[0], e1m[0]);
    aM[1] = fma(C1, g0[1], e0m[1]);  aI[1] = fma(C1, g1[1], e1m[1]);
    aM[2] = fma(C2, g0[2], e0m[2]);  aI[2] = fma(C2, g1[2], e1m[2]);

    // exact exponent-only renorm every 16 steps (target max ~= 2^500;
    // worst growth 2^(17.3*16)=2^277 from 2^500 stays < 2^1023)
    if ((t & 15) == 0) {
      double m = fmax(fmax(fmax(aM[0],aM[1]), fmax(aM[2],aI[0])),
                      fmax(aI[1],aI[2]));
      m = fmax(m, dpp_d<0x111, 0xF, true >(m));
      m = fmax(m, dpp_d<0x112, 0xF, true >(m));
      m = fmax(m, dpp_d<0x114, 0xF, true >(m));
      m = fmax(m, dpp_d<0x118, 0xF, true >(m));
      m = fmax(m, dpp_d<0x142, 0xA, false>(m));
      m = fmax(m, dpp_d<0x143, 0xC, false>(m));
      int ehi = __builtin_amdgcn_readlane(__double2hiint(m), 63);
      int er  = (ehi >> 20) & 0x7FF;
      int dl  = er ? (1523 - er) : 0;     // multiply by 2^dl -> max ~ 2^500
      acc2i -= dl;
      double sc = __hiloint2double((1023 + dl) << 20, 0);
#pragma unroll
      for (int j = 0; j < 3; ++j) { aM[j] *= sc; aI[j] *= sc; }
    }
    cur = nxt; nxt = nn;
  }

  // final: undo reweighting per state (log2 a = log2 a~ + B*log2e*mp + acc2)
  double l2[6];
#pragma unroll
  for (int j = 0; j < 3; ++j) {
    double vm = aM[j], vi = aI[j];
    double w = BETA * LOG2E * (double)(mp0 + j);
    l2[j]   = (vm > 0.0 ? log2(vm) + w : -1.0e300);
    l2[3+j] = (vi > 0.0 ? log2(vi) + w : -1.0e300);
  }
  double lm = l2[0];
#pragma unroll
  for (int j = 1; j < 6; ++j) lm = fmax(lm, l2[j]);
#pragma unroll
  for (int r = 0; r < 6; ++r) lm = fmax(lm, __shfl_xor(lm, 1 << r));
  lm = fmax(lm, -1.0e280);
  double s = 0.0;
#pragma unroll
  for (int j = 0; j < 6; ++j) s += exp2(l2[j] - lm);
#pragma unroll
  for (int r = 0; r < 6; ++r) s += __shfl_xor(s, 1 << r);
  if (lane == 0) {
    // correction: -255*BETA nats (e^{B t} reweight at t=255)
    out[n] = (float)(LN2*(lm + (double)acc2i + log2(s)) - 255.0*BETA);
  }
}

// ---------------------------------------------------------------- launch --
extern "C" void kernel_launch(void* const* d_in, const int* in_sizes, int n_in,
                              void* d_out, int out_size, void* d_ws, size_t ws_size,
                              hipStream_t stream) {
  const float* anc  = (const float*)d_in[0];
  const float* insq = (const float*)d_in[1];
  const float* rr   = (const float*)d_in[2];
  const float* uu   = (const float*)d_in[3];
  const float* data = (const float*)d_in[4];
  float* out = (float*)d_out;

  int*    tokoff = (int*)d_ws;
  double* tabd   = (double*)((char*)d_ws + TABD_OFF);
  double* emd    = (double*)((char*)d_ws + EMD_OFF);

  hipLaunchKernelGGL(prep_tok_kernel, dim3(1+NSEQ), dim3(LSEQ), 0, stream,
                     anc, insq, rr, uu, data, tabd, emd, tokoff);
  hipLaunchKernelGGL(fwd_kernel,      dim3(NSEQ),   dim3(64),   0, stream,
                     tabd, emd, tokoff, out);
}

// Round 8
// 60.139 us; speedup vs baseline: 2.4428x; 1.4123x over previous
//
#include <hip/hip_runtime.h>

#define MT    132      // padded (M+1): 129 valid + 3 zero pad
#define NSEQ  512
#define LSEQ  256
#define MM    128      // M
#define NROW  129      // M+1
#define BETA  10.0     // reweighting: track a * e^{BETA*(t - mp)}
#define LOG2E 1.4426950408889634
#define LN2   0.6931471805599453

// per-mp transition tables (indexed by i = chain/source index), REWEIGHTED
enum { T_TMX=0, T_TIX, T_TMEQ0, T_TIEQ0, T_TMEQ1, T_TIEQ1,
       T_ENT0, T_ENT1, T_STP, T_I0, T_I1, T_COUNT };          // 11

// ws layout: [int tokoff NSEQ*LSEQ] [tabd doubles] [emd doubles, 16B-aligned]
#define TOKI_BYTES (NSEQ*LSEQ*4)          // 524288
#define TABD_OFF   TOKI_BYTES
#define TABD_CNT   (T_COUNT*MT)           // 1452 doubles
#define EMD_OFF    (TABD_OFF + TABD_CNT*8) // 16-aligned
#define EMD_ROW_B  (MT*16)                // 2112 bytes per token row (col pairs)

// DPP ctrl encodings (gfx9/CDNA): ROW_SHR:d = 0x110+d, WAVE_SHR1 = 0x138,
// ROW_BCAST15 = 0x142, ROW_BCAST31 = 0x143.  (HW-verified rounds 4/7.)
template <int CTRL, int RMASK, bool BC>
__device__ __forceinline__ double dpp_d(double v) {
  int lo = __double2loint(v), hi = __double2hiint(v);
  lo = __builtin_amdgcn_update_dpp(0, lo, CTRL, RMASK, 0xF, BC);
  hi = __builtin_amdgcn_update_dpp(0, hi, CTRL, RMASK, 0xF, BC);
  return __hiloint2double(hi, lo);
}

__device__ __forceinline__ double lse2d(double a, double b) {
  double m = fmax(a, b);
  return m + log(exp(a - m) + exp(b - m));
}

// ---------------------------------------------------------- prep + tok ----
__global__ void prep_tok_kernel(const float* __restrict__ anc,
                                const float* __restrict__ insq,
                                const float* __restrict__ rr,
                                const float* __restrict__ uu,
                                const float* __restrict__ data,
                                double* __restrict__ tabd,
                                double* __restrict__ emd,
                                int* __restrict__ tokoff) {
  const int tid = threadIdx.x;
  if (blockIdx.x != 0) {
    // ---- token decode: one thread per position, float4 loads ----
    const int n = blockIdx.x - 1;
    const float4* p = (const float4*)(data + (size_t)(n*LSEQ + tid)*24);
    int tok = 24;
#pragma unroll
    for (int q = 0; q < 6; ++q) {
      float4 v = p[q];
      if (v.x > 0.5f) tok = 4*q+0;
      if (v.y > 0.5f) tok = 4*q+1;
      if (v.z > 0.5f) tok = 4*q+2;
      if (v.w > 0.5f) tok = 4*q+3;
    }
    tokoff[n*LSEQ + tid] = tok * EMD_ROW_B;   // byte offset of token row
    return;
  }

  // ---- block 0: tables ----
  __shared__ double ls[T_COUNT*MT];
  if (tid < MT) {
    double v[T_COUNT];
#pragma unroll
    for (int k = 0; k < T_COUNT; ++k) v[k] = 0.0;
    if (tid <= MM) {
      const int m = tid;
      double rn[3][2], un[3][2];
#pragma unroll
      for (int j = 0; j < 3; ++j) {
        double a0 = (double)rr[(m*3+j)*2+0], a1 = (double)rr[(m*3+j)*2+1];
        double l  = lse2d(a0, a1);
        rn[j][0] = a0 - l; rn[j][1] = a1 - l;
        double b0 = (double)uu[(m*3+j)*2+0], b1 = (double)uu[(m*3+j)*2+1];
        double l2 = lse2d(b0, b1);
        un[j][0] = b0 - l2; un[j][1] = b1 - l2;
      }
      v[T_TMX]   = exp(rn[0][0] + un[0][1] - BETA);  // match exit -> chain  (x e^-B)
      v[T_TIX]   = exp(rn[1][0] + un[1][1]);         // insert exit -> chain
      v[T_TMEQ0] = exp(rn[0][0] + un[0][0]);         // match -> (i,0)
      v[T_TIEQ0] = exp(rn[1][0] + un[1][0] + BETA);  // insert -> (i,0)      (x e^+B)
      v[T_TMEQ1] = exp(rn[0][1]);                    // match -> (i,1)
      v[T_TIEQ1] = exp(rn[1][1] + BETA);             // insert -> (i,1)      (x e^+B)
      v[T_ENT0]  = exp(rn[2][0] + un[2][0]);         // chain -> (mp,0)
      v[T_ENT1]  = exp(rn[2][1]);                    // chain -> (mp,1)
      v[T_STP]   = exp(rn[2][0] + un[2][1] - BETA);  // chain continue       (x e^-B)
    }
#pragma unroll
    for (int k = 0; k < T_COUNT; ++k) ls[k*MT + tid] = v[k];
  }
  __syncthreads();

  if (tid == 0) {   // initial dist (virtual source i=0,j=0), reweighted tables
    ls[T_I0*MT+0] = ls[T_TMEQ0*MT+0];
    ls[T_I1*MT+0] = ls[T_TMEQ1*MT+0];
    double c = ls[T_TMX*MT+0];
    for (int mp = 1; mp <= MM; ++mp) {
      ls[T_I0*MT+mp] = c * ls[T_ENT0*MT+mp];
      ls[T_I1*MT+mp] = c * ls[T_ENT1*MT+mp];
      c *= ls[T_STP*MT+mp];
    }
  }
  __syncthreads();

  for (int i = tid; i < T_COUNT*MT; i += blockDim.x) tabd[i] = ls[i];

  // ---- interleaved emission table: emd[(d*MT+col)*2 + {0:match,1:ins}] ----
  if (tid < NROW) {
    const int m = tid;
    const float* sa = anc  + m*24;
    const float* si = insq + m*24;
    float mxa = -1e30f, mxi = -1e30f;
    for (int d = 0; d < 24; ++d) { mxa = fmaxf(mxa, sa[d]); mxi = fmaxf(mxi, si[d]); }
    float ssa = 0.f, ssi = 0.f;
    for (int d = 0; d < 24; ++d) { ssa += __expf(sa[d]-mxa); ssi += __expf(si[d]-mxi); }
    float ia = 1.f/ssa, ii = 1.f/ssi;
    for (int d = 0; d < 24; ++d) {
      emd[(d*MT+m)*2+0] = (double)(__expf(sa[d]-mxa)*ia);
      emd[(d*MT+m)*2+1] = (double)(__expf(si[d]-mxi)*ii);
    }
    emd[(24*MT+m)*2+0] = 1.0;   // masked token row
    emd[(24*MT+m)*2+1] = 1.0;
  }
  // pad cols 129..131, all 25 token rows
  for (int i = tid; i < 25*3; i += blockDim.x) {
    int d = i/3, c = NROW + i%3;
    emd[(d*MT+c)*2+0] = 0.0;
    emd[(d*MT+c)*2+1] = 0.0;
  }
}

// ---------------------------------------------------------------- fwd -----
// fp64 recurrence (survival window ~beta*M nats -> fp64 mandatory).
// TRUNCATED delete-chain: stp ~ e^{-20}; contributions jumping >5 positions
// in one transition are <= e^{-60} relative to their split/matched
// alternatives (math in journal) -> the 6-round cross-lane scan is replaced
// by the in-lane composite + a single 1-lane carry C0 = wave_shr(x).
struct E6 { double2 a, b, c; };

__global__ __launch_bounds__(64)
void fwd_kernel(const double* __restrict__ tabd,
                const double* __restrict__ emd,
                const int* __restrict__ tokoff,
                float* __restrict__ out) {
  __shared__ int ldsT[LSEQ];
  const int lane = threadIdx.x;
  const int n    = blockIdx.x;

  const int* tp = tokoff + n*LSEQ;
  for (int i = lane; i < LSEQ; i += 64) ldsT[i] = tp[i];

  const int mp0 = 3*lane;
  double tmx[3], tix[3], te0m[3], te0i[3], te1m[3], te1i[3],
         en0[3], en1[3], stpd[3], i0v[3], i1v[3];
#pragma unroll
  for (int j = 0; j < 3; ++j) {
    int mp = mp0 + j;
    bool ok = mp < MT;
    int ix = ok ? mp : 0;
    tmx[j]  = ok ? tabd[T_TMX  *MT+ix] : 0.0;
    tix[j]  = ok ? tabd[T_TIX  *MT+ix] : 0.0;
    te0m[j] = ok ? tabd[T_TMEQ0*MT+ix] : 0.0;
    te0i[j] = ok ? tabd[T_TIEQ0*MT+ix] : 0.0;
    te1m[j] = ok ? tabd[T_TMEQ1*MT+ix] : 0.0;
    te1i[j] = ok ? tabd[T_TIEQ1*MT+ix] : 0.0;
    en0[j]  = ok ? tabd[T_ENT0 *MT+ix] : 0.0;
    en1[j]  = ok ? tabd[T_ENT1 *MT+ix] : 0.0;
    stpd[j] = ok ? tabd[T_STP  *MT+ix] : 0.0;
    i0v[j]  = ok ? tabd[T_I0   *MT+ix] : 0.0;
    i1v[j]  = ok ? tabd[T_I1   *MT+ix] : 0.0;
  }
  const double stp0  = stpd[0], stp1 = stpd[1];
  const double s2v   = stpd[2];
  const double s12   = stpd[1]*stpd[2];
  const double stp01 = stpd[0]*stpd[1];
  __syncthreads();

  // per-lane emission base (clamped so pad lanes stay in-bounds; their
  // tables are all-zero so the values read are never used)
  const int lx = (lane < 44) ? lane : 43;
  const char* emB = (const char*)emd + (size_t)lx*48;
  auto loadE = [&](int t) {
    int off = ldsT[t];
    E6 e;
    e.a = *(const double2*)(emB + off);
    e.b = *(const double2*)(emB + off + 16);
    e.c = *(const double2*)(emB + off + 32);
    return e;
  };

  // initial alpha (reweighted linear domain, fp64)
  double aM0, aM1, aM2, aI0, aI1, aI2;
  {
    E6 e0 = loadE(0);
    aM0 = i0v[0]*e0.a.x;  aI0 = i1v[0]*e0.a.y;
    aM1 = i0v[1]*e0.b.x;  aI1 = i1v[1]*e0.b.y;
    aM2 = i0v[2]*e0.c.x;  aI2 = i1v[2]*e0.c.y;
  }
  int acc2i = 0;

  auto STEP = [&](const E6& cur) {
    const double em0 = cur.a.x, em1 = cur.b.x, em2 = cur.c.x;
    const double ei0 = cur.a.y, ei1 = cur.b.y, ei2 = cur.c.y;

    double ap0 = dpp_d<0x138, 0xF, true>(aM2);   // wave_shr:1, lane0 -> 0
    // off-chain (previous-step state only):
    double xi0 = aI0*tix[0], xi1 = aI1*tix[1], xi2 = aI2*tix[2];
    double X1  = fma(aM0, tmx[1], xi1);
    double X2  = fma(aM1, tmx[2], xi2);
    double xx  = fma(X1, s2v, X2);
    double e01 = fma(aM0, te0m[1], aI1*te0i[1]);
    double e02 = fma(aM1, te0m[2], aI2*te0i[2]);
    double e11 = fma(aM0, te1m[1], aI1*te1i[1]);
    double e12 = fma(aM1, te1m[2], aI2*te1i[2]);
    double g02 = en0[2]*em2, q02 = e02*em2;      // j=2 M-side pre-mult (chain)
    // ap0-dependent:
    double e00 = fma(ap0, te0m[0], aI0*te0i[0]);
    double e10 = fma(ap0, te1m[0], aI0*te1i[0]);
    double X0  = fma(ap0, tmx[0], xi0);
    double x   = fma(X0, s12, xx);               // in-lane chain composite
    double pre = fma(X0, stp1, X1);
    double C0  = dpp_d<0x138, 0xF, true>(x);     // 1-lane carry (truncated)
    double C1  = fma(C0, stp0,  X0);
    double C2  = fma(C0, stp01, pre);
    aM2 = fma(C2, g02, q02);                     // critical: 1 fma after C2
    aM0 = fma(C0, en0[0], e00) * em0;
    aM1 = fma(C1, en0[1], e01) * em1;
    aI0 = fma(C0, en1[0], e10) * ei0;
    aI1 = fma(C1, en1[1], e11) * ei1;
    aI2 = fma(C2, en1[2], e12) * ei2;
  };

  auto RENORM = [&]() {   // exact exponent-only renorm, target max ~= 2^500
    double m = fmax(fmax(fmax(aM0,aM1), fmax(aM2,aI0)), fmax(aI1,aI2));
    m = fmax(m, dpp_d<0x111, 0xF, true >(m));
    m = fmax(m, dpp_d<0x112, 0xF, true >(m));
    m = fmax(m, dpp_d<0x114, 0xF, true >(m));
    m = fmax(m, dpp_d<0x118, 0xF, true >(m));
    m = fmax(m, dpp_d<0x142, 0xA, false>(m));
    m = fmax(m, dpp_d<0x143, 0xC, false>(m));
    int ehi = __builtin_amdgcn_readlane(__double2hiint(m), 63);
    int er  = (ehi >> 20) & 0x7FF;
    int dl  = er ? (1523 - er) : 0;     // multiply by 2^dl -> max ~ 2^500
    acc2i -= dl;
    double sc = __hiloint2double((1023 + dl) << 20, 0);
    aM0 *= sc; aM1 *= sc; aM2 *= sc;
    aI0 *= sc; aI1 *= sc; aI2 *= sc;
  };

  // 3-deep rotating emission prefetch; grouped-by-3 loop (255 = 85*3 steps)
  E6 b0 = loadE(1), b1 = loadE(2), b2 = loadE(3);
  for (int tb = 1; tb + 2 < LSEQ; tb += 3) {
    STEP(b0);
    b0 = loadE(tb+3 < LSEQ ? tb+3 : LSEQ-1);
    if (((tb  ) & 15) == 0) RENORM();
    STEP(b1);
    b1 = loadE(tb+4 < LSEQ ? tb+4 : LSEQ-1);
    if (((tb+1) & 15) == 0) RENORM();
    STEP(b2);
    b2 = loadE(tb+5 < LSEQ ? tb+5 : LSEQ-1);
    if (((tb+2) & 15) == 0) RENORM();
  }

  // final: undo reweighting per state (log2 a = log2 a~ + B*log2e*mp + acc2)
  double aMv[3] = {aM0, aM1, aM2}, aIv[3] = {aI0, aI1, aI2};
  double l2[6];
#pragma unroll
  for (int j = 0; j < 3; ++j) {
    double vm = aMv[j], vi = aIv[j];
    double w = BETA * LOG2E * (double)(mp0 + j);
    l2[j]   = (vm > 0.0 ? log2(vm) + w : -1.0e300);
    l2[3+j] = (vi > 0.0 ? log2(vi) + w : -1.0e300);
  }
  double lm = l2[0];
#pragma unroll
  for (int j = 1; j < 6; ++j) lm = fmax(lm, l2[j]);
#pragma unroll
  for (int r = 0; r < 6; ++r) lm = fmax(lm, __shfl_xor(lm, 1 << r));
  lm = fmax(lm, -1.0e280);
  double s = 0.0;
#pragma unroll
  for (int j = 0; j < 6; ++j) s += exp2(l2[j] - lm);
#pragma unroll
  for (int r = 0; r < 6; ++r) s += __shfl_xor(s, 1 << r);
  if (lane == 0) {
    // correction: -255*BETA nats (e^{B t} reweight at t=255)
    out[n] = (float)(LN2*(lm + (double)acc2i + log2(s)) - 255.0*BETA);
  }
}

// ---------------------------------------------------------------- launch --
extern "C" void kernel_launch(void* const* d_in, const int* in_sizes, int n_in,
                              void* d_out, int out_size, void* d_ws, size_t ws_size,
                              hipStream_t stream) {
  const float* anc  = (const float*)d_in[0];
  const float* insq = (const float*)d_in[1];
  const float* rr   = (const float*)d_in[2];
  const float* uu   = (const float*)d_in[3];
  const float* data = (const float*)d_in[4];
  float* out = (float*)d_out;

  int*    tokoff = (int*)d_ws;
  double* tabd   = (double*)((char*)d_ws + TABD_OFF);
  double* emd    = (double*)((char*)d_ws + EMD_OFF);

  hipLaunchKernelGGL(prep_tok_kernel, dim3(1+NSEQ), dim3(LSEQ), 0, stream,
                     anc, insq, rr, uu, data, tabd, emd, tokoff);
  hipLaunchKernelGGL(fwd_kernel,      dim3(NSEQ),   dim3(64),   0, stream,
                     tabd, emd, tokoff, out);
}